// Round 2
// baseline (210.156 us; speedup 1.0000x reference)
//
#include <hip/hip_runtime.h>
#include <math.h>

// Exact Euclidean distance transform, 1536x1536, matching the Meijster
// reference (scipy.ndimage.distance_transform_edt semantics).
//
// Phase 1 (edt_vscan): per-column down-scan and up-scan of
//   d[i] = bg ? 0 : min(d[i-1]+1, BIG).
//   Down results -> d_out (scratch), up results -> d_ws.
//   One thread per column per direction (3072 threads), coalesced row accesses.
//
// Phase 2 (edt_hpass): one block per row. Stage g2 = min(down,up)^2 into LDS,
//   then exact windowed min-plus search: best = g2[j]; expand dk while
//   dk^2 < best (early exit is exact since any candidate at offset dk costs
//   >= dk^2). On random 50%-bg input g is tiny so this is ~1-3 iters/pixel.
//   All values are integers < 2^24 -> fp32-exact, matching the jnp reference.

#define RR 1536
#define CC 1536
#define BIGF 3072.0f   // R + C, matches reference BIG

__global__ __launch_bounds__(256) void edt_vscan(
    const float* __restrict__ mask,
    float* __restrict__ down,   // = d_out (scratch)
    float* __restrict__ up)     // = d_ws
{
    int tid = blockIdx.x * blockDim.x + threadIdx.x;
    if (tid < CC) {
        // top -> bottom
        int j = tid;
        float carry = BIGF;
        #pragma unroll 4
        for (int i = 0; i < RR; ++i) {
            float m = mask[i * CC + j];
            float d = (m == 0.0f) ? 0.0f : fminf(carry + 1.0f, BIGF);
            down[i * CC + j] = d;
            carry = d;
        }
    } else if (tid < 2 * CC) {
        // bottom -> top
        int j = tid - CC;
        float carry = BIGF;
        #pragma unroll 4
        for (int i = RR - 1; i >= 0; --i) {
            float m = mask[i * CC + j];
            float d = (m == 0.0f) ? 0.0f : fminf(carry + 1.0f, BIGF);
            up[i * CC + j] = d;
            carry = d;
        }
    }
}

__global__ __launch_bounds__(256) void edt_hpass(
    const float* __restrict__ down,
    const float* __restrict__ up,
    float* __restrict__ out)    // may alias `down` -- safe: staged via LDS
{
    __shared__ float g2[CC];
    const int row = blockIdx.x;
    const int t = threadIdx.x;
    const float* __restrict__ drow = down + (size_t)row * CC;
    const float* __restrict__ urow = up + (size_t)row * CC;

    for (int c = t; c < CC; c += 256) {
        float g = fminf(drow[c], urow[c]);
        g2[c] = g * g;
    }
    __syncthreads();

    float res[CC / 256];
    #pragma unroll
    for (int m = 0; m < CC / 256; ++m) {
        int j = t + m * 256;
        float best = g2[j];
        int dk = 1;
        while ((float)(dk * dk) < best) {
            float dk2 = (float)(dk * dk);
            int kl = j - dk;
            int kr = j + dk;
            bool any = false;
            if (kl >= 0) { best = fminf(best, g2[kl] + dk2); any = true; }
            if (kr < CC) { best = fminf(best, g2[kr] + dk2); any = true; }
            if (!any) break;   // window fell off both row ends
            ++dk;
        }
        res[m] = sqrtf(best);
    }

    float* __restrict__ orow = out + (size_t)row * CC;
    #pragma unroll
    for (int m = 0; m < CC / 256; ++m) {
        orow[t + m * 256] = res[m];
    }
}

extern "C" void kernel_launch(void* const* d_in, const int* in_sizes, int n_in,
                              void* d_out, int out_size, void* d_ws, size_t ws_size,
                              hipStream_t stream) {
    const float* mask = (const float*)d_in[0];
    float* out = (float*)d_out;
    float* up = (float*)d_ws;          // needs RR*CC*4 = 9.44 MB of ws

    // Phase 1: 2*CC threads (down-scanners + up-scanners)
    edt_vscan<<<(2 * CC + 255) / 256, 256, 0, stream>>>(mask, out, up);
    // Phase 2: one block per row
    edt_hpass<<<RR, 256, 0, stream>>>(out, up, out);
}

// Round 3
// 77.937 us; speedup vs baseline: 2.6965x; 2.6965x over previous
//
#include <hip/hip_runtime.h>
#include <math.h>

// Exact EDT 1536x1536 (Meijster / scipy.distance_transform_edt semantics).
//
// Round-3 change: phase 1 (vertical distance) was a single serial scan per
// column (1536-deep dependency chain, 48 waves, 0.5% occupancy, 176 us).
// Replaced with a decoupled chunk scan:
//   K1 edt_sum:   per (chunk=32 rows, col): a = dist from chunk top to first
//                 bg row (BIG if none), b = dist from chunk bottom to last bg.
//   K2 edt_carry: per column, 48-step serial scan over chunk summaries to get
//                 the incoming down-carry / up-carry of every chunk.
//                 Exact because an in-chunk bg (<=31) always beats any carry
//                 path (>=32): carry' = (b<BIG) ? b : min(carry+32, BIG).
//   K3 edt_fill:  per (chunk, col): 32-step down scan (carry-seeded) into
//                 registers, then up scan, combine g=min(down,up), write g2.
// Phase 2 (edt_hpass) unchanged: exact expanding-window min-plus with early
// exit (any candidate at offset dk costs >= dk^2, so dk^2 >= best is final).
// All values integers < 2^24 -> fp32-exact; absmax was 0.0 last round.

#define RR 1536
#define CC 1536
#define BIGF 3072.0f    // R + C, matches reference BIG
#define H   32          // chunk height
#define NCH 48          // chunks per column (H*NCH == RR)

__global__ __launch_bounds__(256) void edt_sum(
    const float* __restrict__ mask,
    float* __restrict__ A,    // [NCH][CC] dist chunk-top -> first bg (BIGF if none)
    float* __restrict__ B)    // [NCH][CC] dist chunk-bottom -> last bg
{
    const int col = blockIdx.x * 256 + threadIdx.x;
    const int ch  = blockIdx.y;
    const float* __restrict__ p = mask + (size_t)(ch * H) * CC + col;
    float a = BIGF, b = BIGF;
    #pragma unroll
    for (int ri = 0; ri < H; ++ri) {
        bool bg = (p[ri * CC] == 0.0f);
        a = bg ? fminf(a, (float)ri) : a;
        b = bg ? (float)(H - 1 - ri) : b;
    }
    A[ch * CC + col] = a;
    B[ch * CC + col] = b;
}

__global__ __launch_bounds__(256) void edt_carry(
    const float* __restrict__ A,
    const float* __restrict__ B,
    float* __restrict__ CD,   // [NCH][CC] down-carry entering each chunk
    float* __restrict__ CU)   // [NCH][CC] up-carry entering each chunk
{
    const int tid = blockIdx.x * 256 + threadIdx.x;
    if (tid < CC) {
        const int col = tid;
        float carry = BIGF;                       // d[-1]
        for (int c = 0; c < NCH; ++c) {
            CD[c * CC + col] = carry;
            float b = B[c * CC + col];
            carry = (b < BIGF) ? b : fminf(carry + (float)H, BIGF);
        }
    } else if (tid < 2 * CC) {
        const int col = tid - CC;
        float carry = BIGF;                       // u[RR]
        for (int c = NCH - 1; c >= 0; --c) {
            CU[c * CC + col] = carry;
            float a = A[c * CC + col];
            carry = (a < BIGF) ? a : fminf(carry + (float)H, BIGF);
        }
    }
}

__global__ __launch_bounds__(256) void edt_fill(
    const float* __restrict__ mask,
    const float* __restrict__ CD,
    const float* __restrict__ CU,
    float* __restrict__ g2)   // = d_out (scratch)
{
    const int col = blockIdx.x * 256 + threadIdx.x;
    const int ch  = blockIdx.y;
    const float* __restrict__ p = mask + (size_t)(ch * H) * CC + col;
    float d[H];
    float prev = CD[ch * CC + col];
    #pragma unroll
    for (int ri = 0; ri < H; ++ri) {
        float m = p[ri * CC];
        float dd = (m == 0.0f) ? 0.0f : fminf(prev + 1.0f, BIGF);
        d[ri] = dd;
        prev = dd;
    }
    float up = CU[ch * CC + col];
    float* __restrict__ q = g2 + (size_t)(ch * H) * CC + col;
    #pragma unroll
    for (int ri = H - 1; ri >= 0; --ri) {
        float u = (d[ri] == 0.0f) ? 0.0f : fminf(up + 1.0f, BIGF);
        up = u;
        float g = fminf(d[ri], u);
        q[ri * CC] = g * g;
    }
}

__global__ __launch_bounds__(256) void edt_hpass(
    const float* __restrict__ g2in,
    float* __restrict__ out)   // aliases g2in -- safe: staged via LDS
{
    __shared__ float g2[CC];
    const int row = blockIdx.x;
    const int t = threadIdx.x;
    const float* __restrict__ grow = g2in + (size_t)row * CC;

    for (int c = t; c < CC; c += 256) g2[c] = grow[c];
    __syncthreads();

    float res[CC / 256];
    #pragma unroll
    for (int m = 0; m < CC / 256; ++m) {
        int j = t + m * 256;
        float best = g2[j];
        int dk = 1;
        while ((float)(dk * dk) < best) {
            float dk2 = (float)(dk * dk);
            int kl = j - dk;
            int kr = j + dk;
            bool any = false;
            if (kl >= 0)  { best = fminf(best, g2[kl] + dk2); any = true; }
            if (kr < CC)  { best = fminf(best, g2[kr] + dk2); any = true; }
            if (!any) break;
            ++dk;
        }
        res[m] = sqrtf(best);
    }

    float* __restrict__ orow = out + (size_t)row * CC;
    #pragma unroll
    for (int m = 0; m < CC / 256; ++m) orow[t + m * 256] = res[m];
}

extern "C" void kernel_launch(void* const* d_in, const int* in_sizes, int n_in,
                              void* d_out, int out_size, void* d_ws, size_t ws_size,
                              hipStream_t stream) {
    const float* mask = (const float*)d_in[0];
    float* out = (float*)d_out;

    // workspace layout: 4 arrays of NCH*CC floats = 1.18 MB total
    float* A  = (float*)d_ws;
    float* B  = A  + NCH * CC;
    float* CD = B  + NCH * CC;
    float* CU = CD + NCH * CC;

    dim3 gridc(CC / 256, NCH);
    edt_sum  <<<gridc, 256, 0, stream>>>(mask, A, B);
    edt_carry<<<(2 * CC + 255) / 256, 256, 0, stream>>>(A, B, CD, CU);
    edt_fill <<<gridc, 256, 0, stream>>>(mask, CD, CU, out);   // g2 -> d_out
    edt_hpass<<<RR, 256, 0, stream>>>(out, out);
}